// Round 2
// baseline (1344.699 us; speedup 1.0000x reference)
//
#include <hip/hip_runtime.h>
#include <type_traits>

typedef __attribute__((ext_vector_type(8))) short  vshort8;
typedef __attribute__((ext_vector_type(8))) __bf16 vbf16x8;
typedef __attribute__((ext_vector_type(4))) float  vfloat4;

__device__ __forceinline__ float bf2f(unsigned short h) {
    return __uint_as_float(((unsigned int)h) << 16);
}
__device__ __forceinline__ unsigned short f2bf(float f) {
    unsigned int u = __float_as_uint(f);
    unsigned int r = (u + 0x7FFFu + ((u >> 16) & 1u)) >> 16;
    return (unsigned short)r;
}
// load 8 consecutive fp32, round-to-nearest-even to bf16
__device__ __forceinline__ vshort8 cvt8(const float* p) {
    float4 a = *(const float4*)p;
    float4 b = *(const float4*)(p + 4);
    vshort8 r;
    r[0] = (short)f2bf(a.x); r[1] = (short)f2bf(a.y);
    r[2] = (short)f2bf(a.z); r[3] = (short)f2bf(a.w);
    r[4] = (short)f2bf(b.x); r[5] = (short)f2bf(b.y);
    r[6] = (short)f2bf(b.z); r[7] = (short)f2bf(b.w);
    return r;
}

// ---------------------------------------------------------------------------
// GEMM: C[M][N] = A[M][K] * B[K][N]. A: fp32 or bf16(ushort); B: fp32 weights;
// C: bf16(ushort) or fp32. bf16 MFMA, fp32 accumulate.
// Block tile 64x64, BK=32, 256 threads (4 waves as 2x2 of 32x32 wave tiles).
// ---------------------------------------------------------------------------
template<typename AT, typename CT>
__global__ __launch_bounds__(256) void gemm_kernel(
    const AT* __restrict__ A, const float* __restrict__ B,
    CT* __restrict__ C, int K, int lda, int ldb, int ldc)
{
    __shared__ __align__(16) unsigned short As[64][40];
    __shared__ __align__(16) unsigned short Bs[64][40];   // Bs[n][k]

    const int t    = threadIdx.x;
    const int lane = t & 63;
    const int w    = t >> 6;
    const int wrow = w >> 1, wcol = w & 1;
    const int lm   = lane & 15, quad = lane >> 4;
    const int m0   = blockIdx.y * 64, n0 = blockIdx.x * 64;

    vfloat4 acc00 = {0,0,0,0}, acc01 = {0,0,0,0};
    vfloat4 acc10 = {0,0,0,0}, acc11 = {0,0,0,0};

    const int arow = t >> 2, aseg = t & 3;   // A: 64 rows x 4 segs of 8
    const int brow = t >> 3, bseg = t & 7;   // B: 32 rows x 8 segs of 8

    for (int k0 = 0; k0 < K; k0 += 32) {
        {   // stage A (rows along k)
            if constexpr (std::is_same_v<AT, unsigned short>) {
                vshort8 v = *(const vshort8*)(A + (size_t)(m0 + arow) * lda + k0 + aseg * 8);
                *(vshort8*)&As[arow][aseg * 8] = v;
            } else {
                *(vshort8*)&As[arow][aseg * 8] =
                    cvt8(A + (size_t)(m0 + arow) * lda + k0 + aseg * 8);
            }
        }
        {   // stage B transposed: Bs[n][k], converting fp32 -> bf16
            const float* bp = B + (size_t)(k0 + brow) * ldb + n0 + bseg * 8;
            float4 x = *(const float4*)bp;
            float4 y = *(const float4*)(bp + 4);
            Bs[bseg * 8 + 0][brow] = f2bf(x.x);
            Bs[bseg * 8 + 1][brow] = f2bf(x.y);
            Bs[bseg * 8 + 2][brow] = f2bf(x.z);
            Bs[bseg * 8 + 3][brow] = f2bf(x.w);
            Bs[bseg * 8 + 4][brow] = f2bf(y.x);
            Bs[bseg * 8 + 5][brow] = f2bf(y.y);
            Bs[bseg * 8 + 6][brow] = f2bf(y.z);
            Bs[bseg * 8 + 7][brow] = f2bf(y.w);
        }
        __syncthreads();

        vbf16x8 a0 = *(const vbf16x8*)&As[wrow * 32 +      lm][quad * 8];
        vbf16x8 a1 = *(const vbf16x8*)&As[wrow * 32 + 16 + lm][quad * 8];
        vbf16x8 b0 = *(const vbf16x8*)&Bs[wcol * 32 +      lm][quad * 8];
        vbf16x8 b1 = *(const vbf16x8*)&Bs[wcol * 32 + 16 + lm][quad * 8];
        acc00 = __builtin_amdgcn_mfma_f32_16x16x32_bf16(a0, b0, acc00, 0, 0, 0);
        acc01 = __builtin_amdgcn_mfma_f32_16x16x32_bf16(a0, b1, acc01, 0, 0, 0);
        acc10 = __builtin_amdgcn_mfma_f32_16x16x32_bf16(a1, b0, acc10, 0, 0, 0);
        acc11 = __builtin_amdgcn_mfma_f32_16x16x32_bf16(a1, b1, acc11, 0, 0, 0);
        __syncthreads();
    }

    #pragma unroll
    for (int r = 0; r < 4; ++r) {
        int r0 = m0 + wrow * 32 + quad * 4 + r;
        int r1 = r0 + 16;
        int c0 = n0 + wcol * 32 + lm;
        int c1 = c0 + 16;
        if constexpr (std::is_same_v<CT, float>) {
            C[(size_t)r0 * ldc + c0] = acc00[r];
            C[(size_t)r0 * ldc + c1] = acc01[r];
            C[(size_t)r1 * ldc + c0] = acc10[r];
            C[(size_t)r1 * ldc + c1] = acc11[r];
        } else {
            C[(size_t)r0 * ldc + c0] = f2bf(acc00[r]);
            C[(size_t)r0 * ldc + c1] = f2bf(acc01[r]);
            C[(size_t)r1 * ldc + c0] = f2bf(acc10[r]);
            C[(size_t)r1 * ldc + c1] = f2bf(acc11[r]);
        }
    }
}

// ---------------------------------------------------------------------------
// RMSNorm (bf16 activations, fp32 weight): out = x * rsqrt(mean(x^2)+eps) * w
// ---------------------------------------------------------------------------
__global__ __launch_bounds__(256) void rmsnorm_kernel(
    const unsigned short* __restrict__ in, const float* __restrict__ wgt,
    unsigned short* __restrict__ out, int width, int ld_in, int ld_out)
{
    const int row = blockIdx.x;
    const int t = threadIdx.x;
    const unsigned short* x = in + (size_t)row * ld_in;

    float ss = 0.f;
    for (int i = t; i < width; i += 256) { float v = bf2f(x[i]); ss += v * v; }
    #pragma unroll
    for (int off = 32; off > 0; off >>= 1) ss += __shfl_down(ss, off, 64);

    __shared__ float red[4];
    __shared__ float rr;
    if ((t & 63) == 0) red[t >> 6] = ss;
    __syncthreads();
    if (t == 0) rr = rsqrtf((red[0] + red[1] + red[2] + red[3]) / (float)width + 1e-6f);
    __syncthreads();
    float r = rr;
    unsigned short* o = out + (size_t)row * ld_out;
    for (int i = t; i < width; i += 256) o[i] = f2bf(bf2f(x[i]) * r * wgt[i]);
}

// ---------------------------------------------------------------------------
// RoPE on q_pe (in place) + fold SCALE=192^-0.5 into all of q.
// q layout: [token 4096][h*192 + d], pe at d in [128,192), pairs (i, i+32).
// cos/sin are fp32 [2048][64].
// ---------------------------------------------------------------------------
__global__ __launch_bounds__(256) void rope_q_kernel(
    unsigned short* __restrict__ q, const float* __restrict__ cosb,
    const float* __restrict__ sinb)
{
    const int row = blockIdx.x;
    const int s = row & 2047;
    const int t = threadIdx.x;
    unsigned short* qr = q + (size_t)row * 3072;
    const float SCALE = 0.07216878364870323f;  // 192^-0.5

    for (int c = t; c < 3072; c += 256) {
        int d = c % 192;
        if (d < 128) {
            qr[c] = f2bf(bf2f(qr[c]) * SCALE);
        } else if (d < 160) {
            int i = d - 128;
            float cs = cosb[s * 64 + i];
            float sn = sinb[s * 64 + i];
            float x = bf2f(qr[c]);
            float y = bf2f(qr[c + 32]);
            qr[c]      = f2bf((x * cs - y * sn) * SCALE);
            qr[c + 32] = f2bf((y * cs + x * sn) * SCALE);
        }
        // d in [160,192): written by the pair owner above
    }
}

// ---------------------------------------------------------------------------
// RoPE on k_pe: ckv[:, 512:576] -> kpe[token][64]  (shared across heads)
// ---------------------------------------------------------------------------
__global__ __launch_bounds__(64) void rope_k_kernel(
    const unsigned short* __restrict__ ckv, const float* __restrict__ cosb,
    const float* __restrict__ sinb, unsigned short* __restrict__ kpe)
{
    const int row = blockIdx.x;
    const int s = row & 2047;
    const int t = threadIdx.x;
    if (t < 32) {
        float cs = cosb[s * 64 + t];
        float sn = sinb[s * 64 + t];
        float x = bf2f(ckv[(size_t)row * 576 + 512 + t]);
        float y = bf2f(ckv[(size_t)row * 576 + 544 + t]);
        kpe[(size_t)row * 64 + t]      = f2bf(x * cs - y * sn);
        kpe[(size_t)row * 64 + 32 + t] = f2bf(y * cs + x * sn);
    }
}

// ---------------------------------------------------------------------------
// Causal flash attention (all activations bf16/ushort, fp32 softmax state).
// Q: [token][h*192+d] (scaled+roped). KV: [token][h*256+d] (d<128 K_nope,
// d>=128 V). KPE: [token][64]. O: [token][h*128+d].
// Block = 256 thr (4 waves), Q-tile 64 rows (16/wave), K-tile 64.
// ---------------------------------------------------------------------------
__global__ __launch_bounds__(256) void flash_kernel(
    const unsigned short* __restrict__ Q, const unsigned short* __restrict__ KV,
    const unsigned short* __restrict__ KPE, unsigned short* __restrict__ O)
{
    __shared__ __align__(16) unsigned short Ks[64][192];   // K rows along d
    __shared__ __align__(16) unsigned short Vt[128][64];   // V transposed [d][k]
    __shared__ __align__(16) unsigned short Ps[4][16][64]; // per-wave P strip

    const int t    = threadIdx.x;
    const int lane = t & 63;
    const int w    = t >> 6;
    const int lm   = lane & 15, quad = lane >> 4;
    const int qt = blockIdx.x, h = blockIdx.y, b = blockIdx.z;
    const int tb = b * 2048;

    // Q fragments in registers: wave w owns q rows qt*64 + w*16 + lm
    const int qtok = tb + qt * 64 + w * 16 + lm;
    vbf16x8 aq[6];
    #pragma unroll
    for (int ch = 0; ch < 6; ++ch)
        aq[ch] = *(const vbf16x8*)(Q + (size_t)qtok * 3072 + h * 192 + ch * 32 + quad * 8);

    vfloat4 acc_o[8];
    #pragma unroll
    for (int i = 0; i < 8; ++i) acc_o[i] = (vfloat4){0, 0, 0, 0};
    float mrow[4], lrow[4];
    #pragma unroll
    for (int r = 0; r < 4; ++r) { mrow[r] = -3.0e38f; lrow[r] = 0.f; }

    for (int kt = 0; kt <= qt; ++kt) {
        const int kb = kt * 64;
        // stage K_nope
        for (int idx = t; idx < 64 * 16; idx += 256) {
            int row = idx >> 4, sg = idx & 15;
            vshort8 v = *(const vshort8*)(KV + (size_t)(tb + kb + row) * 4096 + h * 256 + sg * 8);
            *(vshort8*)&Ks[row][sg * 8] = v;
        }
        // stage K_pe
        for (int idx = t; idx < 64 * 8; idx += 256) {
            int row = idx >> 3, sg = idx & 7;
            vshort8 v = *(const vshort8*)(KPE + (size_t)(tb + kb + row) * 64 + sg * 8);
            *(vshort8*)&Ks[row][128 + sg * 8] = v;
        }
        // stage V transposed
        for (int idx = t; idx < 64 * 16; idx += 256) {
            int k = idx >> 4, sg = idx & 15;
            vshort8 v = *(const vshort8*)(KV + (size_t)(tb + kb + k) * 4096 + h * 256 + 128 + sg * 8);
            #pragma unroll
            for (int i = 0; i < 8; ++i) Vt[sg * 8 + i][k] = (unsigned short)v[i];
        }
        __syncthreads();

        // S = Q K^T  (wave strip: 16 q x 64 k)
        vfloat4 accs[4];
        #pragma unroll
        for (int ni = 0; ni < 4; ++ni) accs[ni] = (vfloat4){0, 0, 0, 0};
        #pragma unroll
        for (int ni = 0; ni < 4; ++ni) {
            #pragma unroll
            for (int ch = 0; ch < 6; ++ch) {
                vbf16x8 bk = *(const vbf16x8*)&Ks[ni * 16 + lm][ch * 32 + quad * 8];
                accs[ni] = __builtin_amdgcn_mfma_f32_16x16x32_bf16(aq[ch], bk, accs[ni], 0, 0, 0);
            }
        }

        // causal mask (C layout: q = quad*4+reg, key = ni*16+lm)
        const int qrow = qt * 64 + w * 16 + quad * 4;
        #pragma unroll
        for (int ni = 0; ni < 4; ++ni) {
            int ki = kb + ni * 16 + lm;
            #pragma unroll
            for (int r = 0; r < 4; ++r)
                if (ki > qrow + r) accs[ni][r] = -3.0e38f;
        }

        // online softmax per row (stats replicated across the 16 lm lanes of a quad)
        #pragma unroll
        for (int r = 0; r < 4; ++r) {
            float mx = fmaxf(fmaxf(accs[0][r], accs[1][r]), fmaxf(accs[2][r], accs[3][r]));
            #pragma unroll
            for (int off = 1; off < 16; off <<= 1) mx = fmaxf(mx, __shfl_xor(mx, off, 64));
            float mnew  = fmaxf(mrow[r], mx);
            float alpha = __expf(mrow[r] - mnew);
            float sum = 0.f;
            #pragma unroll
            for (int ni = 0; ni < 4; ++ni) {
                float pv = __expf(accs[ni][r] - mnew);
                accs[ni][r] = pv;
                sum += pv;
            }
            #pragma unroll
            for (int off = 1; off < 16; off <<= 1) sum += __shfl_xor(sum, off, 64);
            lrow[r] = lrow[r] * alpha + sum;
            mrow[r] = mnew;
            #pragma unroll
            for (int vt = 0; vt < 8; ++vt) acc_o[vt][r] *= alpha;
        }

        // P: C-layout -> LDS -> A-layout
        #pragma unroll
        for (int ni = 0; ni < 4; ++ni)
            #pragma unroll
            for (int r = 0; r < 4; ++r)
                Ps[w][quad * 4 + r][ni * 16 + lm] = f2bf(accs[ni][r]);
        __syncthreads();

        // O += P V
        #pragma unroll
        for (int kc = 0; kc < 2; ++kc) {
            vbf16x8 ap = *(const vbf16x8*)&Ps[w][lm][kc * 32 + quad * 8];
            #pragma unroll
            for (int vt = 0; vt < 8; ++vt) {
                vbf16x8 bv = *(const vbf16x8*)&Vt[vt * 16 + lm][kc * 32 + quad * 8];
                acc_o[vt] = __builtin_amdgcn_mfma_f32_16x16x32_bf16(ap, bv, acc_o[vt], 0, 0, 0);
            }
        }
        __syncthreads();
    }

    #pragma unroll
    for (int r = 0; r < 4; ++r) {
        float inv = 1.f / lrow[r];
        int tok = tb + qt * 64 + w * 16 + quad * 4 + r;
        #pragma unroll
        for (int vt = 0; vt < 8; ++vt)
            O[(size_t)tok * 2048 + h * 128 + vt * 16 + lm] = f2bf(acc_o[vt][r] * inv);
    }
}

// ---------------------------------------------------------------------------
extern "C" void kernel_launch(void* const* d_in, const int* in_sizes, int n_in,
                              void* d_out, int out_size, void* d_ws, size_t ws_size,
                              hipStream_t stream) {
    const float* hidden = (const float*)d_in[0];
    // d_in[1] = attention_mask (pure causal by construction; applied analytically)
    const float* cosb   = (const float*)d_in[2];
    const float* sinb   = (const float*)d_in[3];
    const float* w_qa   = (const float*)d_in[4];
    const float* qa_ln  = (const float*)d_in[5];
    const float* w_qb   = (const float*)d_in[6];
    const float* w_kva  = (const float*)d_in[7];
    const float* kva_ln = (const float*)d_in[8];
    const float* w_kvb  = (const float*)d_in[9];
    const float* w_o    = (const float*)d_in[10];
    float* out = (float*)d_out;

    // bf16 intermediates in workspace; lifetimes allow aout to overlap q_a/ckv.
    unsigned short* ws   = (unsigned short*)d_ws;
    unsigned short* q_a  = ws;                               // 4096x1536  [dead after G3]
    unsigned short* ckv  = ws + (size_t)4096 * 1536;         // 4096x576   [dead after rope_k]
    unsigned short* kvn  = ckv + (size_t)4096 * 576;         // 4096x512   [dead after G4]
    unsigned short* kpe  = kvn + (size_t)4096 * 512;         // 4096x64
    unsigned short* qbuf = kpe + (size_t)4096 * 64;          // 4096x3072
    unsigned short* kv   = qbuf + (size_t)4096 * 3072;       // 4096x4096
    unsigned short* aout = ws;                               // 4096x2048 (reuses q_a+ckv)

    dim3 blk(256);

    // G1: q_a = hidden @ w_qa ; G2: ckv = hidden @ w_kva
    gemm_kernel<float, unsigned short><<<dim3(24, 64), blk, 0, stream>>>(hidden, w_qa, q_a, 2048, 2048, 1536, 1536);
    gemm_kernel<float, unsigned short><<<dim3(9, 64), blk, 0, stream>>>(hidden, w_kva, ckv, 2048, 2048, 576, 576);

    // rmsnorms (q_a in place), k_pe rope
    rmsnorm_kernel<<<4096, blk, 0, stream>>>(q_a, qa_ln, q_a, 1536, 1536, 1536);
    rmsnorm_kernel<<<4096, blk, 0, stream>>>(ckv, kva_ln, kvn, 512, 576, 512);
    rope_k_kernel<<<4096, dim3(64), 0, stream>>>(ckv, cosb, sinb, kpe);

    // G3: q = q_a_norm @ w_qb ; rope+scale in place
    gemm_kernel<unsigned short, unsigned short><<<dim3(48, 64), blk, 0, stream>>>(q_a, w_qb, qbuf, 1536, 1536, 3072, 3072);
    rope_q_kernel<<<4096, blk, 0, stream>>>(qbuf, cosb, sinb);

    // G4: kv = kv_norm @ w_kvb
    gemm_kernel<unsigned short, unsigned short><<<dim3(64, 64), blk, 0, stream>>>(kvn, w_kvb, kv, 512, 512, 4096, 4096);

    // attention
    flash_kernel<<<dim3(32, 16, 2), blk, 0, stream>>>(qbuf, kv, kpe, aout);

    // G5: out = attn_out @ w_o  (fp32 output)
    gemm_kernel<unsigned short, float><<<dim3(32, 64), blk, 0, stream>>>(aout, w_o, out, 2048, 2048, 2048, 2048);
}

// Round 6
// 565.171 us; speedup vs baseline: 2.3793x; 2.3793x over previous
//
#include <hip/hip_runtime.h>
#include <type_traits>

typedef __attribute__((ext_vector_type(8))) short  vshort8;
typedef __attribute__((ext_vector_type(8))) __bf16 vbf16x8;
typedef __attribute__((ext_vector_type(4))) float  vfloat4;

__device__ __forceinline__ float bf2f(unsigned short h) {
    return __uint_as_float(((unsigned int)h) << 16);
}
__device__ __forceinline__ unsigned short f2bf(float f) {
    unsigned int u = __float_as_uint(f);
    unsigned int r = (u + 0x7FFFu + ((u >> 16) & 1u)) >> 16;
    return (unsigned short)r;
}
__device__ __forceinline__ vshort8 cvt8(const float* p) {
    float4 a = *(const float4*)p;
    float4 b = *(const float4*)(p + 4);
    vshort8 r;
    r[0] = (short)f2bf(a.x); r[1] = (short)f2bf(a.y);
    r[2] = (short)f2bf(a.z); r[3] = (short)f2bf(a.w);
    r[4] = (short)f2bf(b.x); r[5] = (short)f2bf(b.y);
    r[6] = (short)f2bf(b.z); r[7] = (short)f2bf(b.w);
    return r;
}
// async global->LDS, 16B per lane; LDS base must be wave-uniform.
__device__ __forceinline__ void gload16(const void* g, void* lds) {
    __builtin_amdgcn_global_load_lds(
        (const __attribute__((address_space(1))) unsigned int*)g,
        (__attribute__((address_space(3))) unsigned int*)lds, 16, 0, 0);
}

// ---------------------------------------------------------------------------
// fp32 -> bf16 bulk convert (hidden states)
// ---------------------------------------------------------------------------
__global__ __launch_bounds__(256) void hconv_kernel(
    const float* __restrict__ in, unsigned short* __restrict__ out, int n8)
{
    int i = blockIdx.x * 256 + threadIdx.x;
    if (i < n8) *(vshort8*)(out + (size_t)i * 8) = cvt8(in + (size_t)i * 8);
}

// ---------------------------------------------------------------------------
// Weight transpose+convert: W[K][N] fp32 -> Wt[rowoff+n][K] bf16.
// 64x64 tile, 256 threads: one row-seg (16 elems) per thread on each side.
// (Round 3-5 crash root cause was an i-loop here driving k/n to 111 on a
//  64-row tile -> OOB global writes. Fixed: no loop, t>>2 covers all rows.)
// ---------------------------------------------------------------------------
__global__ __launch_bounds__(256) void wtrans_kernel(
    const float* __restrict__ W, unsigned short* __restrict__ Wt,
    int ldw, int ldt, int rowoff)
{
    __shared__ __align__(16) unsigned short Ls[64][72];
    const int t = threadIdx.x;
    const int n0 = blockIdx.x * 64, k0 = blockIdx.y * 64;
    const int rr = t >> 2, cc = t & 3;   // rr: 0..63, cc: 0..3

    const float* src = W + (size_t)(k0 + rr) * ldw + n0 + cc * 16;
    *(vshort8*)&Ls[rr][cc * 16]     = cvt8(src);
    *(vshort8*)&Ls[rr][cc * 16 + 8] = cvt8(src + 8);
    __syncthreads();

    unsigned short* dst = Wt + (size_t)(rowoff + n0 + rr) * ldt + k0 + cc * 16;
    vshort8 v0, v1;
    #pragma unroll
    for (int j = 0; j < 8; ++j) {
        v0[j] = (short)Ls[cc * 16 + j][rr];
        v1[j] = (short)Ls[cc * 16 + 8 + j][rr];
    }
    *(vshort8*)dst = v0;
    *(vshort8*)(dst + 8) = v1;
}

// ---------------------------------------------------------------------------
// m97-style GEMM: C = A[M][K] * Bt[N][K]^T, both bf16 K-major, fp32 acc.
// 128x128 tile, BK=32, 256 threads, global_load_lds width-16 staging.
// Split epilogue: col < nsplit -> C0, else C1[col-nsplit]. Guard col < N.
// ---------------------------------------------------------------------------
template<typename CT>
__global__ __launch_bounds__(256) void gemm_tt(
    const unsigned short* __restrict__ A, const unsigned short* __restrict__ Bt,
    CT* __restrict__ C0, CT* __restrict__ C1,
    int K, int N, int nsplit, int ldc0, int ldc1)
{
    __shared__ __align__(16) unsigned short As[128 * 32];
    __shared__ __align__(16) unsigned short Bs[128 * 32];

    const int t = threadIdx.x, lane = t & 63, w = t >> 6;
    const int lm = lane & 15, quad = lane >> 4;
    const int wm = w >> 1, wn = w & 1;
    const int m0 = blockIdx.y * 128, n0 = blockIdx.x * 128;
    const int srow = lane >> 2, sseg = lane & 3;

    vfloat4 acc[4][4] = {};

    for (int k0 = 0; k0 < K; k0 += 32) {
        #pragma unroll
        for (int j = 0; j < 2; ++j) {
            int r = w * 32 + j * 16 + srow;
            gload16(A  + (size_t)(m0 + r) * K + k0 + sseg * 8, &As[(w * 2 + j) * 512]);
            gload16(Bt + (size_t)(n0 + r) * K + k0 + sseg * 8, &Bs[(w * 2 + j) * 512]);
        }
        __syncthreads();

        vbf16x8 af[4], bw[4];
        #pragma unroll
        for (int i = 0; i < 4; ++i) {
            af[i] = *(const vbf16x8*)&As[(wm * 64 + i * 16 + lm) * 32 + quad * 8];
            bw[i] = *(const vbf16x8*)&Bs[(wn * 64 + i * 16 + lm) * 32 + quad * 8];
        }
        #pragma unroll
        for (int mi = 0; mi < 4; ++mi)
            #pragma unroll
            for (int ni = 0; ni < 4; ++ni)
                acc[mi][ni] = __builtin_amdgcn_mfma_f32_16x16x32_bf16(af[mi], bw[ni], acc[mi][ni], 0, 0, 0);
        __syncthreads();
    }

    #pragma unroll
    for (int mi = 0; mi < 4; ++mi) {
        #pragma unroll
        for (int ni = 0; ni < 4; ++ni) {
            int col = n0 + wn * 64 + ni * 16 + lm;
            if (col >= N) continue;
            #pragma unroll
            for (int r = 0; r < 4; ++r) {
                int row = m0 + wm * 64 + mi * 16 + quad * 4 + r;
                float v = acc[mi][ni][r];
                if (col < nsplit) {
                    if constexpr (std::is_same_v<CT, float>) C0[(size_t)row * ldc0 + col] = v;
                    else C0[(size_t)row * ldc0 + col] = f2bf(v);
                } else {
                    if constexpr (std::is_same_v<CT, float>) C1[(size_t)row * ldc1 + col - nsplit] = v;
                    else C1[(size_t)row * ldc1 + col - nsplit] = f2bf(v);
                }
            }
        }
    }
}

// ---------------------------------------------------------------------------
// G4 GEMM with scatter epilogue: kv row `row`, col h*256+d.
//   d <  128 -> Kn[row][h*128+d]                    (K_nope, token-major)
//   d >= 128 -> VT[((b*16+h)*128 + d-128)][tok]     (V transposed)
// ---------------------------------------------------------------------------
__global__ __launch_bounds__(256) void gemm_kv(
    const unsigned short* __restrict__ A, const unsigned short* __restrict__ Bt,
    unsigned short* __restrict__ Kn, unsigned short* __restrict__ VT, int K)
{
    __shared__ __align__(16) unsigned short As[128 * 32];
    __shared__ __align__(16) unsigned short Bs[128 * 32];

    const int t = threadIdx.x, lane = t & 63, w = t >> 6;
    const int lm = lane & 15, quad = lane >> 4;
    const int wm = w >> 1, wn = w & 1;
    const int m0 = blockIdx.y * 128, n0 = blockIdx.x * 128;
    const int srow = lane >> 2, sseg = lane & 3;

    vfloat4 acc[4][4] = {};

    for (int k0 = 0; k0 < K; k0 += 32) {
        #pragma unroll
        for (int j = 0; j < 2; ++j) {
            int r = w * 32 + j * 16 + srow;
            gload16(A  + (size_t)(m0 + r) * K + k0 + sseg * 8, &As[(w * 2 + j) * 512]);
            gload16(Bt + (size_t)(n0 + r) * K + k0 + sseg * 8, &Bs[(w * 2 + j) * 512]);
        }
        __syncthreads();

        vbf16x8 af[4], bw[4];
        #pragma unroll
        for (int i = 0; i < 4; ++i) {
            af[i] = *(const vbf16x8*)&As[(wm * 64 + i * 16 + lm) * 32 + quad * 8];
            bw[i] = *(const vbf16x8*)&Bs[(wn * 64 + i * 16 + lm) * 32 + quad * 8];
        }
        #pragma unroll
        for (int mi = 0; mi < 4; ++mi)
            #pragma unroll
            for (int ni = 0; ni < 4; ++ni)
                acc[mi][ni] = __builtin_amdgcn_mfma_f32_16x16x32_bf16(af[mi], bw[ni], acc[mi][ni], 0, 0, 0);
        __syncthreads();
    }

    #pragma unroll
    for (int mi = 0; mi < 4; ++mi) {
        #pragma unroll
        for (int ni = 0; ni < 4; ++ni) {
            int col = n0 + wn * 64 + ni * 16 + lm;
            int h = col >> 8, d = col & 255;
            #pragma unroll
            for (int r = 0; r < 4; ++r) {
                int row = m0 + wm * 64 + mi * 16 + quad * 4 + r;
                float v = acc[mi][ni][r];
                if (d < 128) {
                    Kn[(size_t)row * 2048 + h * 128 + d] = f2bf(v);
                } else {
                    int b = row >> 11, tok = row & 2047;
                    VT[((size_t)(b * 16 + h) * 128 + d - 128) * 2048 + tok] = f2bf(v);
                }
            }
        }
    }
}

// ---------------------------------------------------------------------------
// RMSNorm (bf16 activations, fp32 weight)
// ---------------------------------------------------------------------------
__global__ __launch_bounds__(256) void rmsnorm_kernel(
    const unsigned short* __restrict__ in, const float* __restrict__ wgt,
    unsigned short* __restrict__ out, int width, int ld_in, int ld_out)
{
    const int row = blockIdx.x;
    const int t = threadIdx.x;
    const unsigned short* x = in + (size_t)row * ld_in;

    float ss = 0.f;
    for (int i = t; i < width; i += 256) { float v = bf2f(x[i]); ss += v * v; }
    #pragma unroll
    for (int off = 32; off > 0; off >>= 1) ss += __shfl_down(ss, off, 64);

    __shared__ float red[4];
    __shared__ float rr;
    if ((t & 63) == 0) red[t >> 6] = ss;
    __syncthreads();
    if (t == 0) rr = rsqrtf((red[0] + red[1] + red[2] + red[3]) / (float)width + 1e-6f);
    __syncthreads();
    float r = rr;
    unsigned short* o = out + (size_t)row * ld_out;
    for (int i = t; i < width; i += 256) o[i] = f2bf(bf2f(x[i]) * r * wgt[i]);
}

// ---------------------------------------------------------------------------
// RoPE on q_pe (in place) + fold SCALE=192^-0.5 into all of q.
// ---------------------------------------------------------------------------
__global__ __launch_bounds__(256) void rope_q_kernel(
    unsigned short* __restrict__ q, const float* __restrict__ cosb,
    const float* __restrict__ sinb)
{
    const int row = blockIdx.x;
    const int s = row & 2047;
    const int t = threadIdx.x;
    unsigned short* qr = q + (size_t)row * 3072;
    const float SCALE = 0.07216878364870323f;  // 192^-0.5

    for (int c = t; c < 3072; c += 256) {
        int d = c % 192;
        if (d < 128) {
            qr[c] = f2bf(bf2f(qr[c]) * SCALE);
        } else if (d < 160) {
            int i = d - 128;
            float cs = cosb[s * 64 + i];
            float sn = sinb[s * 64 + i];
            float x = bf2f(qr[c]);
            float y = bf2f(qr[c + 32]);
            qr[c]      = f2bf((x * cs - y * sn) * SCALE);
            qr[c + 32] = f2bf((y * cs + x * sn) * SCALE);
        }
    }
}

// ---------------------------------------------------------------------------
// RoPE on k_pe: ckv[:, 512:576] -> kpe[token][64]
// ---------------------------------------------------------------------------
__global__ __launch_bounds__(64) void rope_k_kernel(
    const unsigned short* __restrict__ ckv, const float* __restrict__ cosb,
    const float* __restrict__ sinb, unsigned short* __restrict__ kpe)
{
    const int row = blockIdx.x;
    const int s = row & 2047;
    const int t = threadIdx.x;
    if (t < 32) {
        float cs = cosb[s * 64 + t];
        float sn = sinb[s * 64 + t];
        float x = bf2f(ckv[(size_t)row * 576 + 512 + t]);
        float y = bf2f(ckv[(size_t)row * 576 + 544 + t]);
        kpe[(size_t)row * 64 + t]      = f2bf(x * cs - y * sn);
        kpe[(size_t)row * 64 + 32 + t] = f2bf(y * cs + x * sn);
    }
}

// ---------------------------------------------------------------------------
// Causal flash attention. Conflict-free LDS (strides 200/72/72), K from Kn,
// V from pre-transposed VT, paired q-tiles (qt, 31-qt) for load balance.
// ---------------------------------------------------------------------------
__global__ __launch_bounds__(256) void flash_kernel(
    const unsigned short* __restrict__ Q, const unsigned short* __restrict__ Kn,
    const unsigned short* __restrict__ KPE, const unsigned short* __restrict__ VT,
    unsigned short* __restrict__ O)
{
    __shared__ __align__(16) unsigned short Ks[64][200];
    __shared__ __align__(16) unsigned short Vs[128][72];
    __shared__ __align__(16) unsigned short Ps[4][16][72];

    const int t    = threadIdx.x;
    const int lane = t & 63;
    const int w    = t >> 6;
    const int lm   = lane & 15, quad = lane >> 4;
    const int h = blockIdx.y, b = blockIdx.z;
    const int tb = b * 2048;
    const unsigned short* VTbh = VT + (size_t)(b * 16 + h) * 128 * 2048;

    for (int pi = 0; pi < 2; ++pi) {
        const int qt = pi ? (31 - blockIdx.x) : blockIdx.x;

        const int qtok = tb + qt * 64 + w * 16 + lm;
        vbf16x8 aq[6];
        #pragma unroll
        for (int ch = 0; ch < 6; ++ch)
            aq[ch] = *(const vbf16x8*)(Q + (size_t)qtok * 3072 + h * 192 + ch * 32 + quad * 8);

        vfloat4 acc_o[8];
        #pragma unroll
        for (int i = 0; i < 8; ++i) acc_o[i] = (vfloat4){0, 0, 0, 0};
        float mrow[4], lrow[4];
        #pragma unroll
        for (int r = 0; r < 4; ++r) { mrow[r] = -3.0e38f; lrow[r] = 0.f; }

        for (int kt = 0; kt <= qt; ++kt) {
            const int kb = kt * 64;
            // stage K_nope (contiguous 128-short rows of Kn)
            #pragma unroll
            for (int it = 0; it < 4; ++it) {
                int idx = t + it * 256;
                int row = idx >> 4, sg = idx & 15;
                *(vshort8*)&Ks[row][sg * 8] =
                    *(const vshort8*)(Kn + (size_t)(tb + kb + row) * 2048 + h * 128 + sg * 8);
            }
            // stage K_pe
            #pragma unroll
            for (int it = 0; it < 2; ++it) {
                int idx = t + it * 256;
                int row = idx >> 3, sg = idx & 7;
                *(vshort8*)&Ks[row][128 + sg * 8] =
                    *(const vshort8*)(KPE + (size_t)(tb + kb + row) * 64 + sg * 8);
            }
            // stage V (already transposed in global: rows d, cols tokens)
            #pragma unroll
            for (int it = 0; it < 4; ++it) {
                int idx = t + it * 256;
                int d = idx >> 3, sg = idx & 7;
                *(vshort8*)&Vs[d][sg * 8] =
                    *(const vshort8*)(VTbh + (size_t)d * 2048 + kb + sg * 8);
            }
            __syncthreads();

            // S = Q K^T (wave strip: 16 q x 64 k)
            vfloat4 accs[4];
            #pragma unroll
            for (int ni = 0; ni < 4; ++ni) accs[ni] = (vfloat4){0, 0, 0, 0};
            #pragma unroll
            for (int ni = 0; ni < 4; ++ni) {
                #pragma unroll
                for (int ch = 0; ch < 6; ++ch) {
                    vbf16x8 bk = *(const vbf16x8*)&Ks[ni * 16 + lm][ch * 32 + quad * 8];
                    accs[ni] = __builtin_amdgcn_mfma_f32_16x16x32_bf16(aq[ch], bk, accs[ni], 0, 0, 0);
                }
            }

            // causal mask
            const int qrow = qt * 64 + w * 16 + quad * 4;
            #pragma unroll
            for (int ni = 0; ni < 4; ++ni) {
                int ki = kb + ni * 16 + lm;
                #pragma unroll
                for (int r = 0; r < 4; ++r)
                    if (ki > qrow + r) accs[ni][r] = -3.0e38f;
            }

            // online softmax
            #pragma unroll
            for (int r = 0; r < 4; ++r) {
                float mx = fmaxf(fmaxf(accs[0][r], accs[1][r]), fmaxf(accs[2][r], accs[3][r]));
                #pragma unroll
                for (int off = 1; off < 16; off <<= 1) mx = fmaxf(mx, __shfl_xor(mx, off, 64));
                float mnew  = fmaxf(mrow[r], mx);
                float alpha = __expf(mrow[r] - mnew);
                float sum = 0.f;
                #pragma unroll
                for (int ni = 0; ni < 4; ++ni) {
                    float pv = __expf(accs[ni][r] - mnew);
                    accs[ni][r] = pv;
                    sum += pv;
                }
                #pragma unroll
                for (int off = 1; off < 16; off <<= 1) sum += __shfl_xor(sum, off, 64);
                lrow[r] = lrow[r] * alpha + sum;
                mrow[r] = mnew;
                #pragma unroll
                for (int vt = 0; vt < 8; ++vt) acc_o[vt][r] *= alpha;
            }

            // P: C-layout -> LDS -> A-layout
            #pragma unroll
            for (int ni = 0; ni < 4; ++ni)
                #pragma unroll
                for (int r = 0; r < 4; ++r)
                    Ps[w][quad * 4 + r][ni * 16 + lm] = f2bf(accs[ni][r]);
            __syncthreads();

            // O += P V
            #pragma unroll
            for (int kc = 0; kc < 2; ++kc) {
                vbf16x8 ap = *(const vbf16x8*)&Ps[w][lm][kc * 32 + quad * 8];
                #pragma unroll
                for (int vt = 0; vt < 8; ++vt) {
                    vbf16x8 bv = *(const vbf16x8*)&Vs[vt * 16 + lm][kc * 32 + quad * 8];
                    acc_o[vt] = __builtin_amdgcn_mfma_f32_16x16x32_bf16(ap, bv, acc_o[vt], 0, 0, 0);
                }
            }
            __syncthreads();
        }

        #pragma unroll
        for (int r = 0; r < 4; ++r) {
            float inv = 1.f / lrow[r];
            int tok = tb + qt * 64 + w * 16 + quad * 4 + r;
            #pragma unroll
            for (int vt = 0; vt < 8; ++vt)
                O[(size_t)tok * 2048 + h * 128 + vt * 16 + lm] = f2bf(acc_o[vt][r] * inv);
        }
    }
}

// ---------------------------------------------------------------------------
extern "C" void kernel_launch(void* const* d_in, const int* in_sizes, int n_in,
                              void* d_out, int out_size, void* d_ws, size_t ws_size,
                              hipStream_t stream) {
    const float* hidden = (const float*)d_in[0];
    // d_in[1] = attention_mask (pure causal; applied analytically)
    const float* cosb   = (const float*)d_in[2];
    const float* sinb   = (const float*)d_in[3];
    const float* w_qa   = (const float*)d_in[4];
    const float* qa_ln  = (const float*)d_in[5];
    const float* w_qb   = (const float*)d_in[6];
    const float* w_kva  = (const float*)d_in[7];
    const float* kva_ln = (const float*)d_in[8];
    const float* w_kvb  = (const float*)d_in[9];
    const float* w_o    = (const float*)d_in[10];
    float* out = (float*)d_out;

    // Workspace overlays (ushort units). Peak 47,185,920 u = 94.4 MB
    // (round-1 proved ws_size >= 97.5 MB by running with that footprint).
    unsigned short* ws   = (unsigned short*)d_ws;
    unsigned short* hb   = ws;                  // 4096x2048 [hconv..G1G2]
    unsigned short* Kn   = ws;                  // 4096x2048 [G4..flash]
    unsigned short* wt12 = ws + 8388608;        // 2176x2048 [prep..G1G2]
    unsigned short* VT   = ws + 8388608;        // 32x128x2048 [G4..flash]
    unsigned short* ot   = ws + 8388608;        // 2048x2048 [post-flash..G5]
    unsigned short* qbuf = ws + 16777216;       // 4096x3072
    unsigned short* q_a  = ws + 29360128;       // 4096x1536 [G1G2..G3]
    unsigned short* ckv  = ws + 35651584;       // 4096x576  [G1G2..rope_k]
    unsigned short* aout = ws + 29360128;       // 4096x2048 [flash..G5]
    unsigned short* qbt  = ws + 38010880;       // 3072x1536
    unsigned short* kvbt = ws + 42729472;       // 4096x512
    unsigned short* kvn  = ws + 44826624;       // 4096x512
    unsigned short* kpe  = ws + 46923776;       // 4096x64   -> end 47185920

    dim3 blk(256);

    // Prepass: hidden -> bf16; weights -> bf16 transposed (N-major rows, K cols)
    hconv_kernel<<<4096, blk, 0, stream>>>(hidden, hb, 1048576);
    wtrans_kernel<<<dim3(24, 32), blk, 0, stream>>>(w_qa,  wt12, 1536, 2048, 0);
    wtrans_kernel<<<dim3( 9, 32), blk, 0, stream>>>(w_kva, wt12,  576, 2048, 1536);
    wtrans_kernel<<<dim3(48, 24), blk, 0, stream>>>(w_qb,  qbt,  3072, 1536, 0);
    wtrans_kernel<<<dim3(64,  8), blk, 0, stream>>>(w_kvb, kvbt, 4096,  512, 0);

    // G1+G2 fused: [q_a | ckv] = hidden @ [w_qa | w_kva]  (N=2112, split 1536)
    gemm_tt<unsigned short><<<dim3(17, 32), blk, 0, stream>>>(
        hb, wt12, q_a, ckv, 2048, 2112, 1536, 1536, 576);

    rmsnorm_kernel<<<4096, blk, 0, stream>>>(q_a, qa_ln, q_a, 1536, 1536, 1536);
    rmsnorm_kernel<<<4096, blk, 0, stream>>>(ckv, kva_ln, kvn, 512, 576, 512);
    rope_k_kernel<<<4096, dim3(64), 0, stream>>>(ckv, cosb, sinb, kpe);

    // G3: qbuf = q_a_norm @ w_qb ; then rope+scale in place
    gemm_tt<unsigned short><<<dim3(24, 32), blk, 0, stream>>>(
        q_a, qbt, qbuf, qbuf, 1536, 3072, 3072, 3072, 3072);
    rope_q_kernel<<<4096, blk, 0, stream>>>(qbuf, cosb, sinb);

    // G4: [Kn | VT] = kv_norm @ w_kvb  (scatter epilogue)
    gemm_kv<<<dim3(32, 32), blk, 0, stream>>>(kvn, kvbt, Kn, VT, 512);

    // attention
    flash_kernel<<<dim3(16, 16, 2), blk, 0, stream>>>(qbuf, Kn, kpe, VT, aout);

    // w_o transpose (deferred: reuses VT region after flash)
    wtrans_kernel<<<dim3(32, 32), blk, 0, stream>>>(w_o, ot, 2048, 2048, 0);

    // G5: out = attn_out @ w_o (fp32 output)
    gemm_tt<float><<<dim3(16, 32), blk, 0, stream>>>(
        aout, ot, out, out, 2048, 2048, 2048, 2048, 2048);
}